// Round 2
// baseline (171.680 us; speedup 1.0000x reference)
//
#include <hip/hip_runtime.h>

#define N_SPIKES 16384
#define N_UNITS  256
#define N_NEIGHB 128
#define RANK     5
#define NC       64
#define NC_OBS   12
#define N_CAND   10
#define DD       60                 // RANK * NC_OBS
#define DD4      15                 // DD / 4
#define OUT_COLS 61
#define OUT_SIZE (N_UNITS * OUT_COLS)   // 15616
#define S_BLOCKS 256                // spike blocks == partial slabs

// ---------------------------------------------------------------------------
// Kernel P: fused nu-gather + matvec.  Lane owns unit u.  (unchanged)
//   nu[d] = mu[u, d/12, obs_ix[h, d%12]]
//   w     = Coo_inv[h] @ nu
//   b     = log_prop[u] - 0.5 * nu.w
// grid = 256 blocks (2 per h, 128 units), block = 128 (2 waves x 64 lanes)
// ---------------------------------------------------------------------------
__global__ __launch_bounds__(128) void precompute_kernel(
    const float* __restrict__ mu, const float* __restrict__ Coo_inv,
    const int* __restrict__ obs_ix, const float* __restrict__ log_prop,
    float* __restrict__ w_buf, float* __restrict__ b_buf)
{
    __shared__ float tile[128 * 61];   // per-lane nu, stride 61 (odd: conflict-free)

    const int h    = blockIdx.x >> 1;
    const int tid  = threadIdx.x;
    const int lane = tid & 63;
    const int wave = tid >> 6;
    const int u    = (blockIdx.x & 1) * 128 + wave * 64 + lane;
    const int p    = h * N_UNITS + u;

    int so[NC_OBS];
#pragma unroll
    for (int j = 0; j < NC_OBS; ++j) so[j] = obs_ix[h * NC_OBS + j];

    const float* __restrict__ mub = mu + u * (RANK * NC);
    float* tl = &tile[tid * 61];
#pragma unroll
    for (int d = 0; d < DD; ++d) {
        const int r = d / NC_OBS;
        const int j = d - r * NC_OBS;
        tl[d] = mub[r * NC + so[j]];
    }

    float wreg[DD];
#pragma unroll
    for (int d = 0; d < DD; ++d) wreg[d] = 0.f;

    const float* __restrict__ C = Coo_inv + h * DD * DD;
    for (int e = 0; e < DD; ++e) {
        const float nu_e = tl[e];                      // ds_read, per-lane
        const float* __restrict__ Crow = C + e * DD;   // wave-uniform -> s_loads
#pragma unroll
        for (int d = 0; d < DD; ++d)
            wreg[d] = fmaf(Crow[d], nu_e, wreg[d]);
    }

    float q2 = 0.f;
#pragma unroll
    for (int d = 0; d < DD; ++d) q2 += wreg[d] * tl[d];

#pragma unroll
    for (int k = 0; k < DD4; ++k) {
        float4 o;
        o.x = wreg[4*k+0]; o.y = wreg[4*k+1];
        o.z = wreg[4*k+2]; o.w = wreg[4*k+3];
        ((float4*)w_buf)[p * DD4 + k] = o;
    }
    b_buf[p] = log_prop[u] - 0.5f * q2;
}

// ---------------------------------------------------------------------------
// Kernel S: per-spike softmax + scatter.  16-lane float4 groups, 4 spikes
// per wave.  256 blocks x 1024 thr = 64 spikes/block (16 waves; LDS 62.5 KB
// -> 1 block/CU, 16 waves/CU -- same occupancy as the 512x512 config).
// Flush: NON-ATOMIC float4 copy of the whole LDS acc into this block's
// private partial slab.  Rationale (R1 counters): the old fire-and-forget
// global f32 atomics write through TCC to HBM as individual 4B RMW
// transactions (WRITE_SIZE 21.5 MB == atomic-count x 4B), each burning a
// >=32B HBM slot => ~50 us.  Coalesced 16 MB write + 16 MB reduce read is
// ~5-8 us of efficient traffic instead.
// use_atomic=1 is a ws_size-too-small fallback (old behavior into out).
// ---------------------------------------------------------------------------
__global__ __launch_bounds__(1024, 2) void spike_kernel(
    const float* __restrict__ features, const float* __restrict__ noise_lp,
    const int* __restrict__ cands, const int* __restrict__ nid,
    const float* __restrict__ w_buf, const float* __restrict__ b_buf,
    float* __restrict__ part_base, const int use_atomic)
{
    __shared__ float acc[OUT_SIZE];
    const int tid = threadIdx.x;
    for (int i = tid; i < OUT_SIZE; i += 1024) acc[i] = 0.f;

    const int lane = tid & 63;
    const int wave = tid >> 6;          // 0..15
    const int l = lane & 15;            // dim-chunk within group
    const int s = lane >> 4;            // spike slot within wave
    const bool dimlane = (l < DD4);     // lanes 0..14 hold float4 dims
    const int n = blockIdx.x * 64 + wave * 4 + s;

    // issue all independent loads up front
    const float4* __restrict__ f4 = (const float4*)features;
    const float4* __restrict__ w4 = (const float4*)w_buf;
    const float4 z4 = {0.f, 0.f, 0.f, 0.f};
    const float4 xf = dimlane ? f4[n * DD4 + l] : z4;
    const int h = nid[n];
    const float nlp = noise_lp[0];
    int uc[N_CAND];
#pragma unroll
    for (int c = 0; c < N_CAND; ++c) uc[c] = cands[n * N_CAND + c];

    float4 wv[N_CAND]; float bb[N_CAND];
#pragma unroll
    for (int c = 0; c < N_CAND; ++c) {
        const int p = h * N_UNITS + uc[c];
        wv[c] = dimlane ? w4[p * DD4 + l] : z4;
        bb[c] = b_buf[p];
    }

    float ll[N_CAND];
#pragma unroll
    for (int c = 0; c < N_CAND; ++c) {
        float t = wv[c].x*xf.x + wv[c].y*xf.y + wv[c].z*xf.z + wv[c].w*xf.w;
        t += __shfl_xor(t, 8, 64);
        t += __shfl_xor(t, 4, 64);
        t += __shfl_xor(t, 2, 64);
        t += __shfl_xor(t, 1, 64);
        ll[c] = bb[c] + t;
    }

    float m = nlp;
#pragma unroll
    for (int c = 0; c < N_CAND; ++c) m = fmaxf(m, ll[c]);
    float ssum = __expf(nlp - m);
    float qv[N_CAND];
#pragma unroll
    for (int c = 0; c < N_CAND; ++c) { qv[c] = __expf(ll[c] - m); ssum += qv[c]; }
    const float inv = 1.f / ssum;

    __syncthreads();   // acc zero-init complete

#pragma unroll
    for (int c = 0; c < N_CAND; ++c) {
        const float q = qv[c] * inv;
        const int ub = uc[c] * OUT_COLS;
        if (dimlane) {
            const int a = ub + 1 + l * 4;
            atomicAdd(&acc[a + 0], q * xf.x);
            atomicAdd(&acc[a + 1], q * xf.y);
            atomicAdd(&acc[a + 2], q * xf.z);
            atomicAdd(&acc[a + 3], q * xf.w);
        } else if (l == DD4) {        // one lane per group: count column
            atomicAdd(&acc[ub], q);
        }
    }

    __syncthreads();

    if (!use_atomic) {
        // non-atomic coalesced flush to this block's private slab
        float4* __restrict__ p4 = (float4*)(part_base + blockIdx.x * OUT_SIZE);
        const float4* __restrict__ a4 = (const float4*)acc;
        for (int i = tid; i < OUT_SIZE / 4; i += 1024) p4[i] = a4[i];
    } else {
        // fallback: fire-and-forget atomics into pre-zeroed out
        for (int i = tid; i < OUT_SIZE; i += 1024) {
            const float v = acc[i];
            if (v != 0.f) atomicAdd(&part_base[i], v);
        }
    }
}

// ---------------------------------------------------------------------------
// Kernel R: sum the 256 partial slabs into d_out.  61 blocks x 256 = one
// thread per output element; reads coalesced across threads, 4 independent
// accumulators to pipeline the 256-deep load chain.  16 MB read, mostly
// L2/L3-resident (just written).  Writes every out element -> no memset.
// ---------------------------------------------------------------------------
__global__ __launch_bounds__(256) void reduce_kernel(
    const float* __restrict__ part, float* __restrict__ out)
{
    const int i = blockIdx.x * 256 + threadIdx.x;   // exact: 61*256 == OUT_SIZE
    float s0 = 0.f, s1 = 0.f, s2 = 0.f, s3 = 0.f;
#pragma unroll 8
    for (int k = 0; k < S_BLOCKS; k += 4) {
        s0 += part[(k + 0) * OUT_SIZE + i];
        s1 += part[(k + 1) * OUT_SIZE + i];
        s2 += part[(k + 2) * OUT_SIZE + i];
        s3 += part[(k + 3) * OUT_SIZE + i];
    }
    out[i] = (s0 + s1) + (s2 + s3);
}

extern "C" void kernel_launch(void* const* d_in, const int* in_sizes, int n_in,
                              void* d_out, int out_size, void* d_ws, size_t ws_size,
                              hipStream_t stream) {
    const float* features    = (const float*)d_in[0];
    const float* mu          = (const float*)d_in[1];
    const float* Coo_inv     = (const float*)d_in[2];
    // d_in[3] = Coo_logdet : unused (cancels in softmax)
    const float* log_prop    = (const float*)d_in[4];
    const float* noise_lp    = (const float*)d_in[5];
    const int*   cands       = (const int*)d_in[6];
    const int*   nid         = (const int*)d_in[7];
    const int*   obs_ix      = (const int*)d_in[8];
    float* out = (float*)d_out;

    char* ws = (char*)d_ws;
    float* w_buf = (float*)ws;                    // 128*256*60*4 = 7,864,320 B
    float* b_buf = (float*)(ws + 7864320);        // 128*256*4    =   131,072 B
    float* part  = (float*)(ws + 7995392);        // 256*15616*4  = 15,990,784 B

    const size_t needed = 7995392 + (size_t)S_BLOCKS * OUT_SIZE * sizeof(float);

    if (ws_size >= needed) {
        precompute_kernel<<<256, 128, 0, stream>>>(mu, Coo_inv, obs_ix, log_prop,
                                                   w_buf, b_buf);
        spike_kernel<<<S_BLOCKS, 1024, 0, stream>>>(features, noise_lp, cands, nid,
                                                    w_buf, b_buf, part, 0);
        reduce_kernel<<<61, 256, 0, stream>>>(part, out);
    } else {
        // workspace too small: old atomic-flush path straight into out
        hipMemsetAsync(d_out, 0, (size_t)out_size * sizeof(float), stream);
        precompute_kernel<<<256, 128, 0, stream>>>(mu, Coo_inv, obs_ix, log_prop,
                                                   w_buf, b_buf);
        spike_kernel<<<S_BLOCKS, 1024, 0, stream>>>(features, noise_lp, cands, nid,
                                                    w_buf, b_buf, out, 1);
    }
}

// Round 3
// 158.494 us; speedup vs baseline: 1.0832x; 1.0832x over previous
//
#include <hip/hip_runtime.h>

#define N_SPIKES 16384
#define N_UNITS  256
#define N_NEIGHB 128
#define RANK     5
#define NC       64
#define NC_OBS   12
#define N_CAND   10
#define DD       60                 // RANK * NC_OBS
#define DD4      15                 // DD / 4
#define OUT_COLS 61
#define OUT_SIZE (N_UNITS * OUT_COLS)   // 15616
#define S_BLOCKS 256                // spike blocks == partial slabs

// ---------------------------------------------------------------------------
// Kernel P v2: d-sliced for occupancy.  v1 ran ONE (h,u) pair per lane ->
// 512 waves total = 2 waves/CU (0.5/SIMD), 3600 FMA + 3600 uniform loads per
// thread, latency fully exposed.  v2 splits d into 4 slices of 15 across
// waves: 8 waves/CU, 900 FMA/thread, nu staged in LDS once per block.
//   block = 512 thr (8 waves): wave = (ug, dq); lane = unit within 64-group
//   grid  = 256 blocks: (h, unit-half)
// Crow rows stay wave-uniform via readfirstlane(dq) -> scalar-cache friendly.
// ---------------------------------------------------------------------------
__global__ __launch_bounds__(512) void precompute_kernel(
    const float* __restrict__ mu, const float* __restrict__ Coo_inv,
    const int* __restrict__ obs_ix, const float* __restrict__ log_prop,
    float* __restrict__ w_buf, float* __restrict__ b_buf)
{
    __shared__ float nu_lds[128 * 61];   // stride 61: 2-way max on reads (free)
    __shared__ float q2_lds[128 * 4];

    const int b   = blockIdx.x;
    const int h   = b >> 1;
    const int ub  = (b & 1) * 128;       // this block's 128 units: ub..ub+127
    const int tid = threadIdx.x;

    // ---- phase 1: gather nu for 128 units into LDS (15 dims per thread) ----
    {
        const int ut  = tid >> 2;        // unit 0..127
        const int dqt = tid & 3;         // dim quarter
        const float* __restrict__ mub = mu + (ub + ut) * (RANK * NC);
#pragma unroll
        for (int j = 0; j < DD4; ++j) {
            const int d = dqt * DD4 + j;
            const int r = d / NC_OBS;
            const int jj = d - r * NC_OBS;
            const int ch = obs_ix[h * NC_OBS + jj];   // L1-broadcast
            nu_lds[ut * 61 + d] = mub[r * NC + ch];
        }
    }
    __syncthreads();

    // ---- phase 2: w slice = Coo_inv[h][:, dq*15..+14]^T . nu ----
    const int lane  = tid & 63;
    const int wave  = tid >> 6;
    const int ug    = wave >> 2;                                  // 0/1
    const int dq    = __builtin_amdgcn_readfirstlane(wave & 3);   // wave-uniform
    const int u_loc = ug * 64 + lane;
    const int u     = ub + u_loc;
    const int p     = h * N_UNITS + u;

    const float* __restrict__ Crow_base = Coo_inv + h * DD * DD + dq * DD4;

    float wreg[DD4];
#pragma unroll
    for (int j = 0; j < DD4; ++j) wreg[j] = 0.f;

    for (int e = 0; e < DD; ++e) {
        const float nu_e = nu_lds[u_loc * 61 + e];     // per-lane ds_read
        const float* __restrict__ Crow = Crow_base + e * DD;  // wave-uniform
#pragma unroll
        for (int j = 0; j < DD4; ++j)
            wreg[j] = fmaf(Crow[j], nu_e, wreg[j]);
    }

    float q2 = 0.f;
#pragma unroll
    for (int j = 0; j < DD4; ++j) q2 += wreg[j] * nu_lds[u_loc * 61 + dq * DD4 + j];
    q2_lds[u_loc * 4 + dq] = q2;

    // w slice out (L2 write-merges the 4 quarter-slices into clean lines)
    float* __restrict__ wp = w_buf + p * DD + dq * DD4;
#pragma unroll
    for (int j = 0; j < DD4; ++j) wp[j] = wreg[j];

    __syncthreads();
    if ((wave & 3) == 0) {   // dq==0 waves: one thread per unit finalizes b
        const float q2s = q2_lds[u_loc * 4 + 0] + q2_lds[u_loc * 4 + 1]
                        + q2_lds[u_loc * 4 + 2] + q2_lds[u_loc * 4 + 3];
        b_buf[p] = log_prop[u] - 0.5f * q2s;
    }
}

// ---------------------------------------------------------------------------
// Kernel S v2: candidate-per-lane.  v1 gave each spike 16 lanes x float4-dims
// and reduced each of the 10 candidate dots with a 4-deep DEPENDENT shfl
// chain (40 serial DS ops/wave) -- latency-bound at 4 waves/SIMD with every
// pipe <8% busy.  v2: lane c (0..9) of each 16-lane group owns candidate c,
// dot is 60 in-lane FMAs streamed over float4 pairs (all loads independent),
// softmax = 8 group-wide shuffles total.  Scatter: q*xf via LDS ds_add,
// xf re-loaded L1-hot.  256 blocks x 1024 thr, 64 spikes/block.
// ---------------------------------------------------------------------------
__global__ __launch_bounds__(1024, 2) void spike_kernel(
    const float* __restrict__ features, const float* __restrict__ noise_lp,
    const int* __restrict__ cands, const int* __restrict__ nid,
    const float* __restrict__ w_buf, const float* __restrict__ b_buf,
    float* __restrict__ part_base, const int use_atomic)
{
    __shared__ float acc[OUT_SIZE];
    const int tid = threadIdx.x;
    for (int i = tid; i < OUT_SIZE; i += 1024) acc[i] = 0.f;

    const int lane = tid & 63;
    const int wave = tid >> 6;          // 0..15
    const int c    = lane & 15;         // candidate slot (0..9 active)
    const int s    = lane >> 4;         // spike slot within wave
    const int n    = blockIdx.x * 64 + wave * 4 + s;
    const bool act = (c < N_CAND);
    const int cc   = act ? c : (N_CAND - 1);   // clamp: keeps loads in-bounds

    const float4* __restrict__ f4 = (const float4*)features;
    const float4* __restrict__ w4 = (const float4*)w_buf;

    const int   h   = nid[n];
    const float nlp = noise_lp[0];
    const int   uc  = cands[n * N_CAND + cc];
    const int   p   = h * N_UNITS + uc;
    const float bb  = b_buf[p];

    // in-lane dot: ll = bb + w[p,:] . xf[n,:]
    float t = 0.f;
#pragma unroll
    for (int k = 0; k < DD4; ++k) {
        const float4 wv = w4[p * DD4 + k];
        const float4 xv = f4[n * DD4 + k];   // same addr across group: L1 bcast
        t += wv.x * xv.x + wv.y * xv.y + wv.z * xv.z + wv.w * xv.w;
    }
    float ll = act ? (bb + t) : -3.4e38f;

    // softmax across the 16-lane group (+ noise class)
    float m = ll;
    m = fmaxf(m, __shfl_xor(m, 1, 16));
    m = fmaxf(m, __shfl_xor(m, 2, 16));
    m = fmaxf(m, __shfl_xor(m, 4, 16));
    m = fmaxf(m, __shfl_xor(m, 8, 16));
    m = fmaxf(m, nlp);
    const float e = act ? __expf(ll - m) : 0.f;
    float ssum = e;
    ssum += __shfl_xor(ssum, 1, 16);
    ssum += __shfl_xor(ssum, 2, 16);
    ssum += __shfl_xor(ssum, 4, 16);
    ssum += __shfl_xor(ssum, 8, 16);
    ssum += __expf(nlp - m);
    const float q = e / ssum;

    __syncthreads();   // acc zero-init complete

    if (act) {
        const int ubase = uc * OUT_COLS;
        atomicAdd(&acc[ubase], q);           // count column
#pragma unroll
        for (int k = 0; k < DD4; ++k) {
            const float4 xv = f4[n * DD4 + k];   // L1-hot reload
            const int a = ubase + 1 + 4 * k;
            atomicAdd(&acc[a + 0], q * xv.x);
            atomicAdd(&acc[a + 1], q * xv.y);
            atomicAdd(&acc[a + 2], q * xv.z);
            atomicAdd(&acc[a + 3], q * xv.w);
        }
    }

    __syncthreads();

    if (!use_atomic) {
        // non-atomic coalesced flush to this block's private slab
        float4* __restrict__ p4 = (float4*)(part_base + blockIdx.x * OUT_SIZE);
        const float4* __restrict__ a4 = (const float4*)acc;
        for (int i = tid; i < OUT_SIZE / 4; i += 1024) p4[i] = a4[i];
    } else {
        // fallback: fire-and-forget atomics into pre-zeroed out
        for (int i = tid; i < OUT_SIZE; i += 1024) {
            const float v = acc[i];
            if (v != 0.f) atomicAdd(&part_base[i], v);
        }
    }
}

// ---------------------------------------------------------------------------
// Kernel R v2: 244 blocks (61 chunks x 4 k-quarters), each sums 64 slabs for
// its 256-element chunk and atomicAdds into memset-zeroed out (4 contenders
// per address, 62K atomics total -> negligible).  4x the occupancy and 1/4
// the chain depth of v1's 61-block 256-deep loop.
// ---------------------------------------------------------------------------
__global__ __launch_bounds__(256) void reduce_kernel(
    const float* __restrict__ part, float* __restrict__ out)
{
    const int chunk = blockIdx.x >> 2;
    const int kq    = blockIdx.x & 3;
    const int i     = chunk * 256 + threadIdx.x;   // 61*256 == OUT_SIZE
    const int k0    = kq * 64;
    float s0 = 0.f, s1 = 0.f, s2 = 0.f, s3 = 0.f;
#pragma unroll 4
    for (int k = k0; k < k0 + 64; k += 4) {
        s0 += part[(k + 0) * OUT_SIZE + i];
        s1 += part[(k + 1) * OUT_SIZE + i];
        s2 += part[(k + 2) * OUT_SIZE + i];
        s3 += part[(k + 3) * OUT_SIZE + i];
    }
    atomicAdd(&out[i], (s0 + s1) + (s2 + s3));
}

extern "C" void kernel_launch(void* const* d_in, const int* in_sizes, int n_in,
                              void* d_out, int out_size, void* d_ws, size_t ws_size,
                              hipStream_t stream) {
    const float* features    = (const float*)d_in[0];
    const float* mu          = (const float*)d_in[1];
    const float* Coo_inv     = (const float*)d_in[2];
    // d_in[3] = Coo_logdet : unused (cancels in softmax)
    const float* log_prop    = (const float*)d_in[4];
    const float* noise_lp    = (const float*)d_in[5];
    const int*   cands       = (const int*)d_in[6];
    const int*   nid         = (const int*)d_in[7];
    const int*   obs_ix      = (const int*)d_in[8];
    float* out = (float*)d_out;

    char* ws = (char*)d_ws;
    float* w_buf = (float*)ws;                    // 128*256*60*4 = 7,864,320 B
    float* b_buf = (float*)(ws + 7864320);        // 128*256*4    =   131,072 B
    float* part  = (float*)(ws + 7995392);        // 256*15616*4  = 15,990,784 B

    const size_t needed = 7995392 + (size_t)S_BLOCKS * OUT_SIZE * sizeof(float);

    if (ws_size >= needed) {
        hipMemsetAsync(d_out, 0, (size_t)out_size * sizeof(float), stream);
        precompute_kernel<<<256, 512, 0, stream>>>(mu, Coo_inv, obs_ix, log_prop,
                                                   w_buf, b_buf);
        spike_kernel<<<S_BLOCKS, 1024, 0, stream>>>(features, noise_lp, cands, nid,
                                                    w_buf, b_buf, part, 0);
        reduce_kernel<<<244, 256, 0, stream>>>(part, out);
    } else {
        // workspace too small: atomic-flush path straight into out
        hipMemsetAsync(d_out, 0, (size_t)out_size * sizeof(float), stream);
        precompute_kernel<<<256, 512, 0, stream>>>(mu, Coo_inv, obs_ix, log_prop,
                                                   w_buf, b_buf);
        spike_kernel<<<S_BLOCKS, 1024, 0, stream>>>(features, noise_lp, cands, nid,
                                                    w_buf, b_buf, out, 1);
    }
}

// Round 4
// 116.943 us; speedup vs baseline: 1.4681x; 1.3553x over previous
//
#include <hip/hip_runtime.h>

#define N_SPIKES 16384
#define N_UNITS  256
#define N_NEIGHB 128
#define RANK     5
#define NC       64
#define NC_OBS   12
#define N_CAND   10
#define DD       60                 // RANK * NC_OBS
#define DD4      15                 // DD / 4
#define OUT_COLS 61
#define OUT_SIZE (N_UNITS * OUT_COLS)   // 15616
#define CAP      1024               // per-unit bin capacity (mean 640, sd ~25 -> 15 sigma)
#define CNT_PAD  16                 // one counter per 64B line (avoid L2 same-line RMW chains)

// ---------------------------------------------------------------------------
// Kernel P: unchanged from R3 (d-sliced, 8 waves/CU).
// ---------------------------------------------------------------------------
__global__ __launch_bounds__(512) void precompute_kernel(
    const float* __restrict__ mu, const float* __restrict__ Coo_inv,
    const int* __restrict__ obs_ix, const float* __restrict__ log_prop,
    float* __restrict__ w_buf, float* __restrict__ b_buf)
{
    __shared__ float nu_lds[128 * 61];
    __shared__ float q2_lds[128 * 4];

    const int b   = blockIdx.x;
    const int h   = b >> 1;
    const int ub  = (b & 1) * 128;
    const int tid = threadIdx.x;

    {
        const int ut  = tid >> 2;
        const int dqt = tid & 3;
        const float* __restrict__ mub = mu + (ub + ut) * (RANK * NC);
#pragma unroll
        for (int j = 0; j < DD4; ++j) {
            const int d = dqt * DD4 + j;
            const int r = d / NC_OBS;
            const int jj = d - r * NC_OBS;
            const int ch = obs_ix[h * NC_OBS + jj];
            nu_lds[ut * 61 + d] = mub[r * NC + ch];
        }
    }
    __syncthreads();

    const int lane  = tid & 63;
    const int wave  = tid >> 6;
    const int ug    = wave >> 2;
    const int dq    = __builtin_amdgcn_readfirstlane(wave & 3);
    const int u_loc = ug * 64 + lane;
    const int u     = ub + u_loc;
    const int p     = h * N_UNITS + u;

    const float* __restrict__ Crow_base = Coo_inv + h * DD * DD + dq * DD4;

    float wreg[DD4];
#pragma unroll
    for (int j = 0; j < DD4; ++j) wreg[j] = 0.f;

    for (int e = 0; e < DD; ++e) {
        const float nu_e = nu_lds[u_loc * 61 + e];
        const float* __restrict__ Crow = Crow_base + e * DD;
#pragma unroll
        for (int j = 0; j < DD4; ++j)
            wreg[j] = fmaf(Crow[j], nu_e, wreg[j]);
    }

    float q2 = 0.f;
#pragma unroll
    for (int j = 0; j < DD4; ++j) q2 += wreg[j] * nu_lds[u_loc * 61 + dq * DD4 + j];
    q2_lds[u_loc * 4 + dq] = q2;

    float* __restrict__ wp = w_buf + p * DD + dq * DD4;
#pragma unroll
    for (int j = 0; j < DD4; ++j) wp[j] = wreg[j];

    __syncthreads();
    if ((wave & 3) == 0) {
        const float q2s = q2_lds[u_loc * 4 + 0] + q2_lds[u_loc * 4 + 1]
                        + q2_lds[u_loc * 4 + 2] + q2_lds[u_loc * 4 + 3];
        b_buf[p] = log_prop[u] - 0.5f * q2s;
    }
}

// ---------------------------------------------------------------------------
// Kernel S1: q-compute + bin.  Candidate-per-lane softmax core from v2,
// WITHOUT any LDS accumulator (the R3 theory: all three prior spike kernels
// plateaued at ~64-70us because of the invariant 10M lane-level ds_add_f32
// RMWs; every other pipe read <8% busy).  Each active lane appends its
// (spike, q) record to the candidate unit's bin: ONE global atomicAdd per
// pair (163K total, 64x fewer RMWs, counters padded to 64B lines).
// ---------------------------------------------------------------------------
__global__ __launch_bounds__(1024) void spike_bin_kernel(
    const float* __restrict__ features, const float* __restrict__ noise_lp,
    const int* __restrict__ cands, const int* __restrict__ nid,
    const float* __restrict__ w_buf, const float* __restrict__ b_buf,
    int* __restrict__ gcount, int2* __restrict__ bins)
{
    const int tid  = threadIdx.x;
    const int lane = tid & 63;
    const int wave = tid >> 6;          // 0..15
    const int c    = lane & 15;         // candidate slot (0..9 active)
    const int s    = lane >> 4;         // spike slot within wave
    const int n    = blockIdx.x * 64 + wave * 4 + s;
    const bool act = (c < N_CAND);
    const int cc   = act ? c : (N_CAND - 1);

    const float4* __restrict__ f4 = (const float4*)features;
    const float4* __restrict__ w4 = (const float4*)w_buf;

    const int   h   = nid[n];
    const float nlp = noise_lp[0];
    const int   uc  = cands[n * N_CAND + cc];
    const int   p   = h * N_UNITS + uc;
    const float bb  = b_buf[p];

    float t = 0.f;
#pragma unroll
    for (int k = 0; k < DD4; ++k) {
        const float4 wv = w4[p * DD4 + k];
        const float4 xv = f4[n * DD4 + k];   // same addr across group: L1 bcast
        t += wv.x * xv.x + wv.y * xv.y + wv.z * xv.z + wv.w * xv.w;
    }
    float ll = act ? (bb + t) : -3.4e38f;

    float m = ll;
    m = fmaxf(m, __shfl_xor(m, 1, 16));
    m = fmaxf(m, __shfl_xor(m, 2, 16));
    m = fmaxf(m, __shfl_xor(m, 4, 16));
    m = fmaxf(m, __shfl_xor(m, 8, 16));
    m = fmaxf(m, nlp);
    const float e = act ? __expf(ll - m) : 0.f;
    float ssum = e;
    ssum += __shfl_xor(ssum, 1, 16);
    ssum += __shfl_xor(ssum, 2, 16);
    ssum += __shfl_xor(ssum, 4, 16);
    ssum += __shfl_xor(ssum, 8, 16);
    ssum += __expf(nlp - m);
    const float q = e / ssum;

    if (act && q > 0.f) {
        const int pos = atomicAdd(&gcount[uc * CNT_PAD], 1);
        if (pos < CAP) bins[uc * CAP + pos] = make_int2(n, __float_as_int(q));
    }
}

// ---------------------------------------------------------------------------
// Kernel S2: per-unit gather-accumulate.  One block per unit (256 blocks x
// 512 thr = 8 waves/CU).  Records staged to LDS coalesced; 16-lane groups
// stream pairs: lane l<15 owns float4-chunk l of xsum (REGISTER accumulate,
// zero atomics), lane 15 accumulates the count column.  Reduce: xor-shuffle
// across the 4 groups of each wave, per-wave partials in LDS, wave 0 sums.
// Writes every out element -> no memset of out, no reduce kernel.
// ---------------------------------------------------------------------------
__global__ __launch_bounds__(512) void unit_accum_kernel(
    const float* __restrict__ features, const int* __restrict__ gcount,
    const int2* __restrict__ bins, float* __restrict__ out)
{
    __shared__ int2  rec[CAP];          // 8 KB
    __shared__ float red[8][OUT_COLS];  // per-wave partials, ~2 KB

    const int u   = blockIdx.x;
    const int tid = threadIdx.x;
    int cnt = gcount[u * CNT_PAD];
    cnt = cnt < CAP ? cnt : CAP;

    for (int i = tid; i < cnt; i += 512) rec[i] = bins[u * CAP + i];
    __syncthreads();

    const int lane = tid & 63;
    const int wave = tid >> 6;          // 0..7
    const int g    = tid >> 4;          // group 0..31
    const int l    = lane & 15;

    const float4* __restrict__ f4 = (const float4*)features;
    float4 a = {0.f, 0.f, 0.f, 0.f};
    float sq = 0.f;

#pragma unroll 2
    for (int i = g; i < cnt; i += 32) {
        const int2 r = rec[i];                   // LDS broadcast within group
        const float q = __int_as_float(r.y);
        if (l < DD4) {
            const float4 xv = f4[r.x * DD4 + l]; // 15 lanes: 240B contiguous
            a.x = fmaf(q, xv.x, a.x);
            a.y = fmaf(q, xv.y, a.y);
            a.z = fmaf(q, xv.z, a.z);
            a.w = fmaf(q, xv.w, a.w);
        } else if (l == DD4) {
            sq += q;
        }
    }

    // reduce across the 4 groups within each wave (lanes l, l+16, l+32, l+48)
    a.x += __shfl_xor(a.x, 16, 64);  a.x += __shfl_xor(a.x, 32, 64);
    a.y += __shfl_xor(a.y, 16, 64);  a.y += __shfl_xor(a.y, 32, 64);
    a.z += __shfl_xor(a.z, 16, 64);  a.z += __shfl_xor(a.z, 32, 64);
    a.w += __shfl_xor(a.w, 16, 64);  a.w += __shfl_xor(a.w, 32, 64);
    sq  += __shfl_xor(sq, 16, 64);   sq  += __shfl_xor(sq, 32, 64);

    if (lane < DD4) {                 // group 0 of each wave writes the partial
        red[wave][1 + 4*lane + 0] = a.x;
        red[wave][1 + 4*lane + 1] = a.y;
        red[wave][1 + 4*lane + 2] = a.z;
        red[wave][1 + 4*lane + 3] = a.w;
    } else if (lane == DD4) {
        red[wave][0] = sq;
    }
    __syncthreads();

    if (tid < OUT_COLS) {
        float ssum = 0.f;
#pragma unroll
        for (int w = 0; w < 8; ++w) ssum += red[w][tid];
        out[u * OUT_COLS + tid] = ssum;
    }
}

extern "C" void kernel_launch(void* const* d_in, const int* in_sizes, int n_in,
                              void* d_out, int out_size, void* d_ws, size_t ws_size,
                              hipStream_t stream) {
    const float* features    = (const float*)d_in[0];
    const float* mu          = (const float*)d_in[1];
    const float* Coo_inv     = (const float*)d_in[2];
    // d_in[3] = Coo_logdet : unused (cancels in softmax)
    const float* log_prop    = (const float*)d_in[4];
    const float* noise_lp    = (const float*)d_in[5];
    const int*   cands       = (const int*)d_in[6];
    const int*   nid         = (const int*)d_in[7];
    const int*   obs_ix      = (const int*)d_in[8];
    float* out = (float*)d_out;

    char* ws = (char*)d_ws;
    float* w_buf  = (float*)ws;                   // 128*256*60*4 = 7,864,320 B
    float* b_buf  = (float*)(ws + 7864320);       // 128*256*4    =   131,072 B
    int*   gcount = (int*)(ws + 7995392);         // 256*16*4     =    16,384 B
    int2*  bins   = (int2*)(ws + 8011776);        // 256*1024*8   = 2,097,152 B
                                                  // total          10,108,928 B

    hipMemsetAsync(gcount, 0, N_UNITS * CNT_PAD * sizeof(int), stream);
    precompute_kernel<<<256, 512, 0, stream>>>(mu, Coo_inv, obs_ix, log_prop,
                                               w_buf, b_buf);
    spike_bin_kernel<<<256, 1024, 0, stream>>>(features, noise_lp, cands, nid,
                                               w_buf, b_buf, gcount, bins);
    unit_accum_kernel<<<256, 512, 0, stream>>>(features, gcount, bins, out);
}

// Round 5
// 112.352 us; speedup vs baseline: 1.5281x; 1.0409x over previous
//
#include <hip/hip_runtime.h>

#define N_SPIKES 16384
#define N_UNITS  256
#define N_NEIGHB 128
#define RANK     5
#define NC       64
#define NC_OBS   12
#define N_CAND   10
#define DD       60                 // RANK * NC_OBS
#define DD4      15                 // DD / 4
#define OUT_COLS 61
#define OUT_SIZE (N_UNITS * OUT_COLS)   // 15616
#define NSB      8                  // sub-bins per unit (counter de-contention)
#define SCAP     192                // per-sub-bin capacity (mean 80, sd 8.9 -> 12.5 sigma)
#define CNT_PAD  4                  // 16B per counter
#define CAP      1024               // S2 staging capacity (total over sub-bins; mean 640)

// ---------------------------------------------------------------------------
// Kernel P: d-sliced precompute (8 waves/CU).  Also zeroes gcount (32 ints
// per block), replacing the hipMemsetAsync dispatch -- stream order
// guarantees gcount is zero before S1 starts.
// ---------------------------------------------------------------------------
__global__ __launch_bounds__(512) void precompute_kernel(
    const float* __restrict__ mu, const float* __restrict__ Coo_inv,
    const int* __restrict__ obs_ix, const float* __restrict__ log_prop,
    float* __restrict__ w_buf, float* __restrict__ b_buf,
    int* __restrict__ gcount)
{
    __shared__ float nu_lds[128 * 61];
    __shared__ float q2_lds[128 * 4];

    const int b   = blockIdx.x;
    const int h   = b >> 1;
    const int ub  = (b & 1) * 128;
    const int tid = threadIdx.x;

    if (tid < 32) gcount[b * 32 + tid] = 0;   // 256 blocks x 32 = 8192 ints

    {
        const int ut  = tid >> 2;
        const int dqt = tid & 3;
        const float* __restrict__ mub = mu + (ub + ut) * (RANK * NC);
#pragma unroll
        for (int j = 0; j < DD4; ++j) {
            const int d = dqt * DD4 + j;
            const int r = d / NC_OBS;
            const int jj = d - r * NC_OBS;
            const int ch = obs_ix[h * NC_OBS + jj];
            nu_lds[ut * 61 + d] = mub[r * NC + ch];
        }
    }
    __syncthreads();

    const int lane  = tid & 63;
    const int wave  = tid >> 6;
    const int ug    = wave >> 2;
    const int dq    = __builtin_amdgcn_readfirstlane(wave & 3);
    const int u_loc = ug * 64 + lane;
    const int u     = ub + u_loc;
    const int p     = h * N_UNITS + u;

    const float* __restrict__ Crow_base = Coo_inv + h * DD * DD + dq * DD4;

    float wreg[DD4];
#pragma unroll
    for (int j = 0; j < DD4; ++j) wreg[j] = 0.f;

    for (int e = 0; e < DD; ++e) {
        const float nu_e = nu_lds[u_loc * 61 + e];
        const float* __restrict__ Crow = Crow_base + e * DD;
#pragma unroll
        for (int j = 0; j < DD4; ++j)
            wreg[j] = fmaf(Crow[j], nu_e, wreg[j]);
    }

    float q2 = 0.f;
#pragma unroll
    for (int j = 0; j < DD4; ++j) q2 += wreg[j] * nu_lds[u_loc * 61 + dq * DD4 + j];
    q2_lds[u_loc * 4 + dq] = q2;

    float* __restrict__ wp = w_buf + p * DD + dq * DD4;
#pragma unroll
    for (int j = 0; j < DD4; ++j) wp[j] = wreg[j];

    __syncthreads();
    if ((wave & 3) == 0) {
        const float q2s = q2_lds[u_loc * 4 + 0] + q2_lds[u_loc * 4 + 1]
                        + q2_lds[u_loc * 4 + 2] + q2_lds[u_loc * 4 + 3];
        b_buf[p] = log_prop[u] - 0.5f * q2s;
    }
}

// ---------------------------------------------------------------------------
// Kernel S1: q-compute + bin (candidate-per-lane core).  Sub-bin sb =
// blockIdx&7: 8x fewer increments per counter (640 -> ~80 deep chains).
// One global atomicAdd per (spike,cand) pair; record = (n, q).
// ---------------------------------------------------------------------------
__global__ __launch_bounds__(1024) void spike_bin_kernel(
    const float* __restrict__ features, const float* __restrict__ noise_lp,
    const int* __restrict__ cands, const int* __restrict__ nid,
    const float* __restrict__ w_buf, const float* __restrict__ b_buf,
    int* __restrict__ gcount, int2* __restrict__ bins)
{
    const int tid  = threadIdx.x;
    const int lane = tid & 63;
    const int wave = tid >> 6;          // 0..15
    const int c    = lane & 15;         // candidate slot (0..9 active)
    const int s    = lane >> 4;         // spike slot within wave
    const int n    = blockIdx.x * 64 + wave * 4 + s;
    const int sb   = blockIdx.x & (NSB - 1);
    const bool act = (c < N_CAND);
    const int cc   = act ? c : (N_CAND - 1);

    const float4* __restrict__ f4 = (const float4*)features;
    const float4* __restrict__ w4 = (const float4*)w_buf;

    const int   h   = nid[n];
    const float nlp = noise_lp[0];
    const int   uc  = cands[n * N_CAND + cc];
    const int   p   = h * N_UNITS + uc;
    const float bb  = b_buf[p];

    float t = 0.f;
#pragma unroll
    for (int k = 0; k < DD4; ++k) {
        const float4 wv = w4[p * DD4 + k];
        const float4 xv = f4[n * DD4 + k];   // same addr across group: L1 bcast
        t += wv.x * xv.x + wv.y * xv.y + wv.z * xv.z + wv.w * xv.w;
    }
    float ll = act ? (bb + t) : -3.4e38f;

    float m = ll;
    m = fmaxf(m, __shfl_xor(m, 1, 16));
    m = fmaxf(m, __shfl_xor(m, 2, 16));
    m = fmaxf(m, __shfl_xor(m, 4, 16));
    m = fmaxf(m, __shfl_xor(m, 8, 16));
    m = fmaxf(m, nlp);
    const float e = act ? __expf(ll - m) : 0.f;
    float ssum = e;
    ssum += __shfl_xor(ssum, 1, 16);
    ssum += __shfl_xor(ssum, 2, 16);
    ssum += __shfl_xor(ssum, 4, 16);
    ssum += __shfl_xor(ssum, 8, 16);
    ssum += __expf(nlp - m);
    const float q = e / ssum;

    if (act && q > 0.f) {
        const int bi  = uc * NSB + sb;
        const int pos = atomicAdd(&gcount[bi * CNT_PAD], 1);
        if (pos < SCAP) bins[bi * SCAP + pos] = make_int2(n, __float_as_int(q));
    }
}

// ---------------------------------------------------------------------------
// Kernel S2: per-unit gather-accumulate.  One block per unit, 8 waves.
// Stage: tid<8 reads the 8 sub-bin counts in parallel; thread 0 prefix-sums;
// wave w copies sub-bin w's records into the compact LDS rec[] (wave-parallel
// staging).  Accumulate: 16-lane groups, register xsum per float4-lane,
// xor-shuffle reduce, per-wave LDS partials, final 61-thread sum -> out.
// No atomics anywhere; writes every out element (no memset of out).
// ---------------------------------------------------------------------------
__global__ __launch_bounds__(512) void unit_accum_kernel(
    const float* __restrict__ features, const int* __restrict__ gcount,
    const int2* __restrict__ bins, float* __restrict__ out)
{
    __shared__ int2  rec[CAP];          // 8 KB
    __shared__ float red[8][OUT_COLS];  // ~2 KB
    __shared__ int   cnts[NSB];
    __shared__ int   offs[NSB + 1];

    const int u    = blockIdx.x;
    const int tid  = threadIdx.x;
    const int lane = tid & 63;
    const int wave = tid >> 6;          // 0..7 == sub-bin it stages

    if (tid < NSB) {
        int c = gcount[(u * NSB + tid) * CNT_PAD];
        cnts[tid] = c < SCAP ? c : SCAP;
    }
    __syncthreads();
    if (tid == 0) {
        int o = 0;
#pragma unroll
        for (int sb = 0; sb < NSB; ++sb) { offs[sb] = o; o += cnts[sb]; }
        offs[NSB] = o;
    }
    __syncthreads();

    {   // wave-parallel staging: wave w copies sub-bin w
        const int base = offs[wave];
        const int cnt  = cnts[wave];
        const int2* __restrict__ src = bins + (u * NSB + wave) * SCAP;
        for (int i = lane; i < cnt; i += 64) rec[base + i] = src[i];
    }
    __syncthreads();

    const int total = offs[NSB];
    const int g = tid >> 4;             // group 0..31
    const int l = lane & 15;

    const float4* __restrict__ f4 = (const float4*)features;
    float4 a = {0.f, 0.f, 0.f, 0.f};
    float sq = 0.f;

#pragma unroll 2
    for (int i = g; i < total; i += 32) {
        const int2 r = rec[i];                   // LDS broadcast within group
        const float q = __int_as_float(r.y);
        if (l < DD4) {
            const float4 xv = f4[r.x * DD4 + l]; // 15 lanes: 240B contiguous
            a.x = fmaf(q, xv.x, a.x);
            a.y = fmaf(q, xv.y, a.y);
            a.z = fmaf(q, xv.z, a.z);
            a.w = fmaf(q, xv.w, a.w);
        } else if (l == DD4) {
            sq += q;
        }
    }

    // reduce across the 4 groups within each wave
    a.x += __shfl_xor(a.x, 16, 64);  a.x += __shfl_xor(a.x, 32, 64);
    a.y += __shfl_xor(a.y, 16, 64);  a.y += __shfl_xor(a.y, 32, 64);
    a.z += __shfl_xor(a.z, 16, 64);  a.z += __shfl_xor(a.z, 32, 64);
    a.w += __shfl_xor(a.w, 16, 64);  a.w += __shfl_xor(a.w, 32, 64);
    sq  += __shfl_xor(sq, 16, 64);   sq  += __shfl_xor(sq, 32, 64);

    if (lane < DD4) {                 // group 0 of each wave writes the partial
        red[wave][1 + 4*lane + 0] = a.x;
        red[wave][1 + 4*lane + 1] = a.y;
        red[wave][1 + 4*lane + 2] = a.z;
        red[wave][1 + 4*lane + 3] = a.w;
    } else if (lane == DD4) {
        red[wave][0] = sq;
    }
    __syncthreads();

    if (tid < OUT_COLS) {
        float ssum = 0.f;
#pragma unroll
        for (int w = 0; w < 8; ++w) ssum += red[w][tid];
        out[u * OUT_COLS + tid] = ssum;
    }
}

extern "C" void kernel_launch(void* const* d_in, const int* in_sizes, int n_in,
                              void* d_out, int out_size, void* d_ws, size_t ws_size,
                              hipStream_t stream) {
    const float* features    = (const float*)d_in[0];
    const float* mu          = (const float*)d_in[1];
    const float* Coo_inv     = (const float*)d_in[2];
    // d_in[3] = Coo_logdet : unused (cancels in softmax)
    const float* log_prop    = (const float*)d_in[4];
    const float* noise_lp    = (const float*)d_in[5];
    const int*   cands       = (const int*)d_in[6];
    const int*   nid         = (const int*)d_in[7];
    const int*   obs_ix      = (const int*)d_in[8];
    float* out = (float*)d_out;

    char* ws = (char*)d_ws;
    float* w_buf  = (float*)ws;                   // 128*256*60*4 = 7,864,320 B
    float* b_buf  = (float*)(ws + 7864320);       // 128*256*4    =   131,072 B
    int*   gcount = (int*)(ws + 7995392);         // 256*8*4*4    =    32,768 B
    int2*  bins   = (int2*)(ws + 8028160);        // 256*8*192*8  = 3,145,728 B
                                                  // total          11,173,888 B

    precompute_kernel<<<256, 512, 0, stream>>>(mu, Coo_inv, obs_ix, log_prop,
                                               w_buf, b_buf, gcount);
    spike_bin_kernel<<<256, 1024, 0, stream>>>(features, noise_lp, cands, nid,
                                               w_buf, b_buf, gcount, bins);
    unit_accum_kernel<<<256, 512, 0, stream>>>(features, gcount, bins, out);
}